// Round 5
// baseline (220.931 us; speedup 1.0000x reference)
//
#include <hip/hip_runtime.h>

// LongformerAttention MI355X — Round 4.
// attn: split-K flash-decode for global-row strips (linear partials thanks to
// static-max softmax), maskless fast path for pure-global strips, + combine
// kernel. Window strips unchanged. GEMM/cvt stages unchanged from Round 3.

#define B_   2
#define S_   2048
#define DM   1024
#define H_   16
#define NG   204                     // max(1, int(S*0.1))
#define BS_  4096                    // B_*S_
#define SCL2 0.1803368801111204f     // (1/sqrt(64)) * log2(e)
#define NEGF -3.0e38f

typedef unsigned short u16;
typedef unsigned int   u32;
typedef __attribute__((ext_vector_type(8))) short frag8;   // 8 x bf16
typedef __attribute__((ext_vector_type(4))) float f32x4;

#define MFMA16(A, Bf, C) __builtin_amdgcn_mfma_f32_16x16x32_bf16((A), (Bf), (C), 0, 0, 0)
#define GLD16(g, l)                                                              \
  __builtin_amdgcn_global_load_lds((const __attribute__((address_space(1))) u32*)(g), \
                                   (__attribute__((address_space(3))) u32*)(l), 16, 0, 0)

#if __has_builtin(__builtin_amdgcn_exp2f)
#define EXP2(x) __builtin_amdgcn_exp2f(x)
#else
#define EXP2(x) exp2f(x)
#endif

__device__ __forceinline__ u16 f2bf(float f) {
  union { float f; u32 u; } c; c.f = f;
  u32 u = c.u + 0x7fffu + ((c.u >> 16) & 1u);   // RNE
  return (u16)(u >> 16);
}

// ---------------- fp32 -> bf16 convert, all buffers in one launch ----------------
__global__ void cvt_all(const float* __restrict__ X,  const float* __restrict__ Wq,
                        const float* __restrict__ Wk, const float* __restrict__ Wv,
                        const float* __restrict__ Wo,
                        u16* Xb, u16* Wqb, u16* Wkb, u16* Wvb, u16* Wob) {
  const int chunk = blockIdx.y;
  const float* src; u16* dst;
  if (chunk < 4)      { src = X + (size_t)chunk * 1048576; dst = Xb + (size_t)chunk * 1048576; }
  else if (chunk == 4){ src = Wq; dst = Wqb; }
  else if (chunk == 5){ src = Wk; dst = Wkb; }
  else if (chunk == 6){ src = Wv; dst = Wvb; }
  else                { src = Wo; dst = Wob; }
  int i = blockIdx.x * 256 + threadIdx.x;
  float4 v = ((const float4*)src)[i];
  u32 lo = (u32)f2bf(v.x) | ((u32)f2bf(v.y) << 16);
  u32 hi = (u32)f2bf(v.z) | ((u32)f2bf(v.w) << 16);
  ((uint2*)dst)[i] = make_uint2(lo, hi);
}

// ---------------- m97-style GEMM mainloop, 256 threads, 128x128 tile ----------------
__device__ __forceinline__ void gemm_mainloop(const u16* __restrict__ A, const u16* __restrict__ Bm,
                                              int bm, int bn, u16* As, u16* Bs,
                                              f32x4 acc[4][4]) {
  const int tid = threadIdx.x;
  const int wv = tid >> 6, lane = tid & 63, l15 = lane & 15, quad = lane >> 4;
  const int wm = wv & 1, wn = wv >> 1;

  const u16* gA[4]; const u16* gB[4];
#pragma unroll
  for (int c = 0; c < 4; ++c) {
    int idx = (wv * 4 + c) * 64 + lane;
    int r = idx >> 3;
    int cb = (idx & 7) ^ (r & 7);
    gA[c] = A  + (size_t)(bm + r) * DM + cb * 8;
    gB[c] = Bm + (size_t)(bn + r) * DM + cb * 8;
  }

  int offA[4][2], offB[4][2];
#pragma unroll
  for (int i = 0; i < 4; ++i)
#pragma unroll
    for (int h = 0; h < 2; ++h) {
      int mA = wm * 64 + i * 16 + l15;
      int mB = wn * 64 + i * 16 + l15;
      int cb = (quad + h * 4) ^ (l15 & 7);
      offA[i][h] = ((mA << 3) + cb) << 4;
      offB[i][h] = ((mB << 3) + cb) << 4;
    }

  for (int k0 = 0; k0 < DM; k0 += 64) {
#pragma unroll
    for (int c = 0; c < 4; ++c) {
      GLD16(gA[c] + k0, (char*)As + (wv * 4 + c) * 1024);
      GLD16(gB[c] + k0, (char*)Bs + (wv * 4 + c) * 1024);
    }
    __syncthreads();
    frag8 af[4][2], bf[4][2];
#pragma unroll
    for (int i = 0; i < 4; ++i) {
      af[i][0] = *(const frag8*)((const char*)As + offA[i][0]);
      af[i][1] = *(const frag8*)((const char*)As + offA[i][1]);
      bf[i][0] = *(const frag8*)((const char*)Bs + offB[i][0]);
      bf[i][1] = *(const frag8*)((const char*)Bs + offB[i][1]);
    }
#pragma unroll
    for (int h = 0; h < 2; ++h)
#pragma unroll
      for (int i = 0; i < 4; ++i)
#pragma unroll
        for (int j = 0; j < 4; ++j)
          acc[i][j] = MFMA16(af[i][h], bf[j][h], acc[i][j]);
    __syncthreads();
  }
}

__global__ __launch_bounds__(256, 3) void gemm_qkv(const u16* __restrict__ Xb,
    const u16* __restrict__ Wqb, const u16* __restrict__ Wkb, const u16* __restrict__ Wvb,
    const float* __restrict__ bq, const float* __restrict__ bk, const float* __restrict__ bv,
    u16* __restrict__ Qb, u16* __restrict__ Kb, u16* __restrict__ Vt) {
  __shared__ u16 As[8192], Bs[8192];
  const int bm = blockIdx.y * 128;
  const int which = blockIdx.x >> 3;
  const int bnl = (blockIdx.x & 7) * 128;
  const u16* W = (which == 0) ? Wqb : (which == 1) ? Wkb : Wvb;
  const float* bias = (which == 0) ? bq : (which == 1) ? bk : bv;

  f32x4 acc[4][4] = {};
  gemm_mainloop(Xb, W, bm, bnl, As, Bs, acc);

  const int tid = threadIdx.x, wv = tid >> 6, lane = tid & 63, l15 = lane & 15, quad = lane >> 4;
  const int wm = wv & 1, wn = wv >> 1;
  if (which < 2) {
    u16* O = (which == 0) ? Qb : Kb;
#pragma unroll
    for (int j = 0; j < 4; ++j) {
      int col = bnl + wn * 64 + j * 16 + l15;
      float bb = bias[col];
#pragma unroll
      for (int i = 0; i < 4; ++i) {
        int row0 = bm + wm * 64 + i * 16 + quad * 4;
#pragma unroll
        for (int r = 0; r < 4; ++r)
          O[(size_t)(row0 + r) * DM + col] = f2bf(acc[i][j][r] + bb);
      }
    }
  } else {
#pragma unroll
    for (int j = 0; j < 4; ++j) {
      int col = bnl + wn * 64 + j * 16 + l15;
      float bb = bias[col];
#pragma unroll
      for (int i = 0; i < 4; ++i) {
        int row0 = bm + wm * 64 + i * 16 + quad * 4;
        u32 lo = (u32)f2bf(acc[i][j][0] + bb) | ((u32)f2bf(acc[i][j][1] + bb) << 16);
        u32 hi = (u32)f2bf(acc[i][j][2] + bb) | ((u32)f2bf(acc[i][j][3] + bb) << 16);
        *(uint2*)&Vt[(size_t)col * BS_ + row0] = make_uint2(lo, hi);
      }
    }
  }
}

// ---------------- Wo GEMM: 512 threads (8 waves), 128x128 tile ----------------
__global__ __launch_bounds__(512, 2) void gemm_wo(const u16* __restrict__ Cx,
    const u16* __restrict__ Wob, const float* __restrict__ bo, float* __restrict__ out) {
  __shared__ u16 As[8192], Bs[8192];
  const int bm = blockIdx.y * 128, bn = blockIdx.x * 128;
  const int tid = threadIdx.x;
  const int wv = tid >> 6, lane = tid & 63, l15 = lane & 15, quad = lane >> 4;
  const int wm = wv & 1, wn = wv >> 1;

  const u16* gA[2]; const u16* gB[2];
#pragma unroll
  for (int c = 0; c < 2; ++c) {
    int idx = (wv * 2 + c) * 64 + lane;
    int r = idx >> 3;
    int cb = (idx & 7) ^ (r & 7);
    gA[c] = Cx  + (size_t)(bm + r) * DM + cb * 8;
    gB[c] = Wob + (size_t)(bn + r) * DM + cb * 8;
  }
  int offA[4][2], offB[2][2];
#pragma unroll
  for (int h = 0; h < 2; ++h) {
#pragma unroll
    for (int i = 0; i < 4; ++i) {
      int mA = wm * 64 + i * 16 + l15;
      offA[i][h] = ((mA << 3) + ((quad + h * 4) ^ (l15 & 7))) << 4;
    }
#pragma unroll
    for (int j = 0; j < 2; ++j) {
      int nB = wn * 32 + j * 16 + l15;
      offB[j][h] = ((nB << 3) + ((quad + h * 4) ^ (l15 & 7))) << 4;
    }
  }

  f32x4 acc[4][2] = {};
  for (int k0 = 0; k0 < DM; k0 += 64) {
#pragma unroll
    for (int c = 0; c < 2; ++c) {
      GLD16(gA[c] + k0, (char*)As + (wv * 2 + c) * 1024);
      GLD16(gB[c] + k0, (char*)Bs + (wv * 2 + c) * 1024);
    }
    __syncthreads();
    frag8 af[4][2], bf[2][2];
#pragma unroll
    for (int i = 0; i < 4; ++i) {
      af[i][0] = *(const frag8*)((const char*)As + offA[i][0]);
      af[i][1] = *(const frag8*)((const char*)As + offA[i][1]);
    }
#pragma unroll
    for (int j = 0; j < 2; ++j) {
      bf[j][0] = *(const frag8*)((const char*)Bs + offB[j][0]);
      bf[j][1] = *(const frag8*)((const char*)Bs + offB[j][1]);
    }
#pragma unroll
    for (int h = 0; h < 2; ++h)
#pragma unroll
      for (int i = 0; i < 4; ++i)
#pragma unroll
        for (int j = 0; j < 2; ++j)
          acc[i][j] = MFMA16(af[i][h], bf[j][h], acc[i][j]);
    __syncthreads();
  }

#pragma unroll
  for (int j = 0; j < 2; ++j) {
    int col = bn + wn * 32 + j * 16 + l15;
    float bb = bo[col];
#pragma unroll
    for (int i = 0; i < 4; ++i) {
      int row0 = bm + wm * 64 + i * 16 + quad * 4;
#pragma unroll
      for (int r = 0; r < 4; ++r)
        out[(size_t)(row0 + r) * DM + col] = acc[i][j][r] + bb;
    }
  }
}

// ---------------- Flash attention: split-K for global strips, pipelined ----------------
// Units per bh: 28 split-units (strips 0..6 x 4 segs of 8 tiles) + 57 window
// units (strips 7..63). Grid = 85*32; bh = blk&31 (XCD-pinned), unit = blk>>5.
__global__ __launch_bounds__(128, 2) void attn_kernel(const u16* __restrict__ Q,
                                                      const u16* __restrict__ K,
                                                      const u16* __restrict__ Vt,
                                                      u16* __restrict__ Ctx,
                                                      float* __restrict__ Op,
                                                      float* __restrict__ Lp) {
  __shared__ u16 Ps[2][16][76];

  const int tid = threadIdx.x, w = tid >> 6, lane = tid & 63, l15 = lane & 15, quad = lane >> 4;
  const int blk = blockIdx.x;
  const int bh = blk & 31, unit = blk >> 5;
  const int b = bh >> 4, h = bh & 15;
  const bool split = unit < 28;
  const int strip = split ? (unit >> 2) : (unit - 21);
  const int q0 = strip * 32;
  const int qw = q0 + w * 16;

  const u16* qrow = Q + (size_t)(b * S_ + qw + l15) * DM + h * 64;
  frag8 aq0 = *(const frag8*)(qrow + quad * 8);
  frag8 aq1 = *(const frag8*)(qrow + quad * 8 + 32);

  const u16* kb = K  + (size_t)((size_t)b * S_ + l15) * DM + h * 64 + quad * 8;
  const u16* vb = Vt + (size_t)((size_t)h * 64 + l15) * BS_ + (size_t)b * S_ + quad * 8;

  int qidx[4]; bool qglob[4];
#pragma unroll
  for (int r = 0; r < 4; ++r) { qidx[r] = qw + quad * 4 + r; qglob[r] = qidx[r] < NG; }

  f32x4 o[4] = {};
  float lsum[4] = {0.f, 0.f, 0.f, 0.f};

  auto loadK = [&](int t, frag8* d0, frag8* d1) {
    const u16* kp = kb + (size_t)(t * 64) * DM;
#pragma unroll
    for (int kg = 0; kg < 4; ++kg) {
      d0[kg] = *(const frag8*)(kp + (size_t)(kg * 16) * DM);
      d1[kg] = *(const frag8*)(kp + (size_t)(kg * 16) * DM + 32);
    }
  };
  auto loadV = [&](int t, frag8* d0, frag8* d1) {
    const u16* vp = vb + t * 64;
#pragma unroll
    for (int nt = 0; nt < 4; ++nt) {
      d0[nt] = *(const frag8*)(vp + (size_t)(nt * 16) * BS_);
      d1[nt] = *(const frag8*)(vp + (size_t)(nt * 16) * BS_ + 32);
    }
  };
  auto pv = [&](frag8* bv0, frag8* bv1, float pr[4][4]) {
#pragma unroll
    for (int kg = 0; kg < 4; ++kg)
#pragma unroll
      for (int r = 0; r < 4; ++r)
        Ps[w][quad * 4 + r][kg * 16 + l15] = f2bf(pr[kg][r]);
    __asm__ volatile("s_waitcnt lgkmcnt(0)" ::: "memory");
    frag8 ap0 = *(const frag8*)&Ps[w][l15][quad * 8];
    frag8 ap1 = *(const frag8*)&Ps[w][l15][quad * 8 + 32];
#pragma unroll
    for (int nt = 0; nt < 4; ++nt) {
      o[nt] = MFMA16(ap0, bv0[nt], o[nt]);
      o[nt] = MFMA16(ap1, bv1[nt], o[nt]);
    }
  };

  frag8 Ak0[4], Ak1[4], Av0[4], Av1[4];
  frag8 Bk0[4], Bk1[4], Bv0[4], Bv1[4];

  if (split) {
    const int seg = unit & 3;
    const int kt0 = seg * 8;
    const bool domask = (strip == 6);   // rows 192..223 straddle the global cutoff

    auto step_lin = [&](int cur, bool more,
                        frag8* bk0, frag8* bk1, frag8* bv0, frag8* bv1,
                        frag8* nk0, frag8* nk1, frag8* nv0, frag8* nv1) {
      const int k0 = cur * 64;
      f32x4 sc[4] = {};
#pragma unroll
      for (int kg = 0; kg < 4; ++kg) {
        sc[kg] = MFMA16(aq0, bk0[kg], sc[kg]);
        sc[kg] = MFMA16(aq1, bk1[kg], sc[kg]);
      }
      if (more) loadK(cur + 1, nk0, nk1);
      float pr[4][4];
      if (domask) {
#pragma unroll
        for (int kg = 0; kg < 4; ++kg) {
          int kc = k0 + kg * 16 + l15;
          bool kglob = kc < NG;
#pragma unroll
          for (int r = 0; r < 4; ++r) {
            int d = qidx[r] - kc;
            bool act = ((unsigned)(d + 64) <= 128u) || qglob[r] || kglob;
            float p = EXP2(act ? sc[kg][r] * SCL2 : NEGF);
            pr[kg][r] = p; lsum[r] += p;
          }
        }
      } else {                           // pure-global rows: every key attended
#pragma unroll
        for (int kg = 0; kg < 4; ++kg)
#pragma unroll
          for (int r = 0; r < 4; ++r) {
            float p = EXP2(sc[kg][r] * SCL2);
            pr[kg][r] = p; lsum[r] += p;
          }
      }
      if (more) loadV(cur + 1, nv0, nv1);
      pv(bv0, bv1, pr);
    };

    loadK(kt0, Ak0, Ak1);
    loadV(kt0, Av0, Av1);
#pragma unroll
    for (int tt = 0; tt < 8; tt += 2) {
      step_lin(kt0 + tt,     tt + 1 < 8, Ak0, Ak1, Av0, Av1, Bk0, Bk1, Bv0, Bv1);
      step_lin(kt0 + tt + 1, tt + 2 < 8, Bk0, Bk1, Bv0, Bv1, Ak0, Ak1, Av0, Av1);
    }

#pragma unroll
    for (int off = 8; off; off >>= 1)
#pragma unroll
      for (int r = 0; r < 4; ++r) lsum[r] += __shfl_xor(lsum[r], off);

    float* op = Op + ((size_t)((bh * 7 + strip) * 4 + seg)) * 2048;  // 32 rows x 64
    float* lp = Lp + ((size_t)((bh * 7 + strip) * 4 + seg)) * 32;
#pragma unroll
    for (int r = 0; r < 4; ++r) {
      int row_local = w * 16 + quad * 4 + r;
#pragma unroll
      for (int nt = 0; nt < 4; ++nt)
        op[row_local * 64 + nt * 16 + l15] = o[nt][r];
      if (l15 == 0) lp[row_local] = lsum[r];
    }
    return;
  }

  // ---- window path (strips 7..63): generic mask, tile-skip scan ----
  auto activef = [&](int t) {
    int k0 = t * 64;
    return (k0 < NG) || (k0 + 63 >= q0 - 64 && k0 <= q0 + 95);
  };
  auto nextt = [&](int cur) { int n = cur + 1; while (n < 32 && !activef(n)) ++n; return n; };

  auto step = [&](int cur, int nxt, bool more,
                  frag8* bk0, frag8* bk1, frag8* bv0, frag8* bv1,
                  frag8* nk0, frag8* nk1, frag8* nv0, frag8* nv1) {
    const int k0 = cur * 64;
    f32x4 sc[4] = {};
#pragma unroll
    for (int kg = 0; kg < 4; ++kg) {
      sc[kg] = MFMA16(aq0, bk0[kg], sc[kg]);
      sc[kg] = MFMA16(aq1, bk1[kg], sc[kg]);
    }
    if (more) loadK(nxt, nk0, nk1);
    float pr[4][4];
#pragma unroll
    for (int kg = 0; kg < 4; ++kg) {
      int kc = k0 + kg * 16 + l15;
      bool kglob = kc < NG;
#pragma unroll
      for (int r = 0; r < 4; ++r) {
        int d = qidx[r] - kc;
        bool act = ((unsigned)(d + 64) <= 128u) || kglob;   // qglob false here
        float p = EXP2(act ? sc[kg][r] * SCL2 : NEGF);
        pr[kg][r] = p; lsum[r] += p;
      }
    }
    if (more) loadV(nxt, nv0, nv1);
    pv(bv0, bv1, pr);
  };

  int kt = 0;                              // tile 0 always active (global cols)
  loadK(0, Ak0, Ak1);
  loadV(0, Av0, Av1);
  for (;;) {
    int ktn = nextt(kt);
    bool more = ktn < 32;
    step(kt, ktn, more, Ak0, Ak1, Av0, Av1, Bk0, Bk1, Bv0, Bv1);
    if (!more) break;
    kt = ktn;
    ktn = nextt(kt);
    more = ktn < 32;
    step(kt, ktn, more, Bk0, Bk1, Bv0, Bv1, Ak0, Ak1, Av0, Av1);
    if (!more) break;
    kt = ktn;
  }

#pragma unroll
  for (int off = 8; off; off >>= 1)
#pragma unroll
    for (int r = 0; r < 4; ++r) lsum[r] += __shfl_xor(lsum[r], off);

#pragma unroll
  for (int r = 0; r < 4; ++r) {
    float inv = 1.0f / lsum[r];
    int row = qw + quad * 4 + r;
    u16* crow = Ctx + (size_t)((size_t)b * S_ + row) * DM + h * 64;
#pragma unroll
    for (int nt = 0; nt < 4; ++nt)
      crow[nt * 16 + l15] = f2bf(o[nt][r] * inv);
  }
}

// ---------------- combine split-K partials -> Ctx rows 0..223 ----------------
// grid 224: bh = blk&31, strip = blk>>5. 256 thr: row = t>>3, 8 cols each.
__global__ __launch_bounds__(256) void combine_kernel(const float* __restrict__ Op,
                                                      const float* __restrict__ Lp,
                                                      u16* __restrict__ Ctx) {
  const int blk = blockIdx.x;
  const int bh = blk & 31, strip = blk >> 5;
  const int b = bh >> 4, h = bh & 15;
  const int t = threadIdx.x;
  const int row = t >> 3, colg = (t & 7) * 8;

  const float* opb = Op + ((size_t)(bh * 7 + strip) * 4) * 2048;
  const float* lpb = Lp + ((size_t)(bh * 7 + strip) * 4) * 32;

  float l = lpb[row] + lpb[32 + row] + lpb[64 + row] + lpb[96 + row];
  float acc[8];
#pragma unroll
  for (int e = 0; e < 8; ++e) acc[e] = opb[row * 64 + colg + e];
#pragma unroll
  for (int seg = 1; seg < 4; ++seg)
#pragma unroll
    for (int e = 0; e < 8; ++e) acc[e] += opb[seg * 2048 + row * 64 + colg + e];

  float inv = 1.0f / l;
  u32 pk[4];
#pragma unroll
  for (int p = 0; p < 4; ++p)
    pk[p] = (u32)f2bf(acc[2 * p] * inv) | ((u32)f2bf(acc[2 * p + 1] * inv) << 16);
  uint4 vout = make_uint4(pk[0], pk[1], pk[2], pk[3]);
  *(uint4*)&Ctx[(size_t)((size_t)b * S_ + strip * 32 + row) * DM + h * 64 + colg] = vout;
}

// ---------------- launch ----------------
extern "C" void kernel_launch(void* const* d_in, const int* in_sizes, int n_in,
                              void* d_out, int out_size, void* d_ws, size_t ws_size,
                              hipStream_t stream) {
  const float* X  = (const float*)d_in[0];
  const float* Wq = (const float*)d_in[1];
  const float* bq = (const float*)d_in[2];
  const float* Wk = (const float*)d_in[3];
  const float* bk = (const float*)d_in[4];
  const float* Wv = (const float*)d_in[5];
  const float* bv = (const float*)d_in[6];
  const float* Wo = (const float*)d_in[7];
  const float* bo = (const float*)d_in[8];
  float* out = (float*)d_out;

  u16* ws = (u16*)d_ws;
  const size_t NX = (size_t)BS_ * DM;
  const size_t NW = (size_t)DM * DM;
  u16* Xb  = ws;
  u16* Wqb = Xb + NX;
  u16* Wkb = Wqb + NW;
  u16* Wvb = Wkb + NW;
  u16* Wob = Wvb + NW;
  u16* Qb  = Wob + NW;
  u16* Kb  = Qb + NX;
  u16* Vt  = Kb + NX;
  u16* Cx  = Vt + NX;
  float* Op = (float*)(Cx + NX);            // 32*7*4*32*64 = 1.84M floats
  float* Lp = Op + (size_t)32 * 7 * 4 * 2048;  // 28672 floats

  cvt_all<<<dim3(1024, 8), 256, 0, stream>>>(X, Wq, Wk, Wv, Wo, Xb, Wqb, Wkb, Wvb, Wob);
  gemm_qkv<<<dim3(24, 32), 256, 0, stream>>>(Xb, Wqb, Wkb, Wvb, bq, bk, bv, Qb, Kb, Vt);
  attn_kernel<<<85 * 32, 128, 0, stream>>>(Qb, Kb, Vt, Cx, Op, Lp);
  combine_kernel<<<224, 256, 0, stream>>>(Op, Lp, Cx);
  gemm_wo<<<dim3(8, 32), 512, 0, stream>>>(Cx, Wob, bo, out);
}